// Round 21
// baseline (76.771 us; speedup 1.0000x reference)
//
#include <hip/hip_runtime.h>

// BandSplit R21: bs_banded rebuilt as a blocked GEMM. BM=128 x BN=256 per
// 512-thread/8-wave block (waves 2Mx4N, 64x64 out each, acc[4][4]); A-tile
// double-buffered in 18.4KB LDS (1 barrier + 16 MFMA/wave per phase, vs 2
// MFMA/barrier before); B regs from L2-resident Mb (traffic 415->104MB).
// Setup chain unchanged from R18/R20 (cvt | prep | compose | mk_bf16).

#define K_BANDS 64
#define COUT_D  128
#define T_DIM   1024
#define B_DIM   4
#define F_DIM   1025
#define XP      1032     // padded bf16 x row length ([1025,1032) zeroed)
#define WPAD    112      // padded band width (W <= 112, verified R2-R20)
#define DINP    224      // 2*WPAD, channel-blocked j/i = c*112 + wi
#define NMT     14       // DINP/16 tiles (compose geometry)
#define NKTC    4        // 128/32 compose-K tiles
#define CHUNK   128      // output f-bins per chunk
#define NCHUNK  9        // ceil(1025/128)
#define WIN     352      // 112 + 128 + 112 input window
#define K2      704      // 2*WIN
#define KT2     22       // K2/32; phases 0..10 -> c=0, 11..21 -> c=1
#define OC      256      // out cols per chunk (2ch x 128)
#define NCT     16       // OC/16
#define BM      128      // rows per main block
#define SALD    36       // s_a row stride (shorts): 18 dw, odd*2 -> spread

typedef __attribute__((ext_vector_type(8))) short bf16x8;
typedef __attribute__((ext_vector_type(4))) float f32x4;

__device__ __forceinline__ unsigned short f2bf(float f) {
    unsigned u = __builtin_bit_cast(unsigned, f);
    u += 0x7FFFu + ((u >> 16) & 1u);          // RNE
    return (unsigned short)(u >> 16);
}
__device__ __forceinline__ void st8(unsigned short* o, const unsigned short* v) {
    *(ushort4*)(o)     = make_ushort4(v[0], v[1], v[2], v[3]);
    *(ushort4*)(o + 4) = make_ushort4(v[4], v[5], v[6], v[7]);
}

struct alignas(4) f4u { float v[4]; };        // dword-aligned 16B load

// ---- cvt: x f32 -> padded bf16 x_bf rows of XP; also zero Mf+bias.
__global__ __launch_bounds__(256) void bs_cvt(
    const float* __restrict__ x, unsigned short* __restrict__ x_bf,
    float* __restrict__ zbase, int zcount)
{
    const int row = blockIdx.x;               // (b*2+c)*1024 + t
    const int tid = threadIdx.x;
    {
        const int i = blockIdx.x * 256 + tid;
        if (i < zcount) zbase[i] = 0.f;
    }
    const float* src = x + (size_t)row * F_DIM;
    unsigned short* dst = x_bf + (size_t)row * XP;
    for (int p = tid; p < XP / 4; p += 256) {
        const int f = 4 * p;
        unsigned short v[4];
        if (f + 4 <= F_DIM) {
            const f4u vv = *reinterpret_cast<const f4u*>(src + f);
#pragma unroll
            for (int e = 0; e < 4; ++e) v[e] = f2bf(vv.v[e]);
        } else {
#pragma unroll
            for (int e = 0; e < 4; ++e)
                v[e] = (f + e < F_DIM) ? f2bf(src[f + e]) : (unsigned short)0;
        }
        *(ushort4*)(dst + f) = make_ushort4(v[0], v[1], v[2], v[3]);
    }
}

// ---- prep: pack post' B-frags (k, kt over o, ct over i, lane, 8), * sc(i)
__global__ __launch_bounds__(256) void bs_prep(
    const float* __restrict__ post_w, const int* __restrict__ idx,
    const float* __restrict__ melw, const float* __restrict__ mask,
    const float* __restrict__ ola, unsigned short* __restrict__ dstB,
    int W, int din)
{
    const int k = blockIdx.x, kt = blockIdx.y;
    for (int q = threadIdx.x; q < NMT * 64; q += 256) {
        const int ct = q >> 6, lane = q & 63;
        const int col = lane & 15, kg = lane >> 4;
        const int i  = ct * 16 + col;
        const int cc = (i >= WPAD);
        const int wi = i - cc * WPAD;
        float sc = 0.f;
        if (wi < W) {
            const float mw = melw[k * W + wi] * mask[k * W + wi];
            if (mw != 0.f) sc = 1.0f / ola[idx[k * W + wi]];
        }
        unsigned short v[8];
#pragma unroll
        for (int e = 0; e < 8; ++e) {
            const int o = kt * 32 + kg * 8 + e;
            const float f = (sc != 0.f)
                ? sc * post_w[((size_t)k * COUT_D + o) * din + 2 * wi + cc] : 0.f;
            v[e] = f2bf(f);
        }
        st8(dstB + ((((size_t)k * NKTC + kt) * NMT + ct) * 64 + lane) * 8, v);
    }
}

// ---- compose A_k = pre'^T x post', atomicAdd into banded Mf.
// A-frags built on the fly.  mt in [0,14): compose; mt == 14: bias.
__global__ __launch_bounds__(256) void bs_compose(
    const unsigned short* __restrict__ postP,
    const float* __restrict__ pre_w,  const float* __restrict__ pre_b,
    const float* __restrict__ post_w, const float* __restrict__ post_b,
    const int* __restrict__ idx, const float* __restrict__ melw,
    const float* __restrict__ mask, const float* __restrict__ ola,
    float* __restrict__ Mf, float* __restrict__ bias_g, int W, int din)
{
    __shared__ unsigned char s_flag[DINP];
    const int k   = blockIdx.x;
    const int mt  = blockIdx.y;
    const int tid = threadIdx.x;
    const int f0  = idx[(size_t)k * W];

    if (mt == NMT) {          // bias block
        if (tid >= DINP) return;
        const int c = tid >= WPAD, wi = tid - c * WPAD;
        if (wi >= W) return;
        if (melw[k * W + wi] * mask[k * W + wi] == 0.f) return;
        const int f = idx[k * W + wi];
        float v = post_b[(size_t)k * din + 2 * wi + c];
        for (int o = 0; o < COUT_D; ++o)
            v += pre_b[k * COUT_D + o]
                 * post_w[((size_t)k * COUT_D + o) * din + 2 * wi + c];
        atomicAdd(bias_g + c * F_DIM + f, v / ola[f]);
        return;
    }

    if (tid < DINP) {
        const int cc = tid >= WPAD, wi = tid - cc * WPAD;
        s_flag[tid] = (wi < W) && (melw[k * W + wi] * mask[k * W + wi] != 0.f);
    }
    __syncthreads();

    const int lane = tid & 63, wave = tid >> 6;
    const int col  = lane & 15, kg  = lane >> 4;
    const bf16x8* bp = (const bf16x8*)(postP + (size_t)k * NKTC * NMT * 512);

    bf16x8 a[NKTC];
    {
        const int jl  = mt * 16 + col;
        const int cc2 = jl >= WPAD, wj = jl - cc2 * WPAD;
        float wt = 0.f;
        if (wj < W) wt = melw[k * W + wj] * mask[k * W + wj];
#pragma unroll
        for (int kt = 0; kt < NKTC; ++kt) {
            bf16x8 av = (bf16x8){0, 0, 0, 0, 0, 0, 0, 0};
            if (wt != 0.f) {
                const float* src = pre_w
                    + ((size_t)k * din + 2 * wj + cc2) * COUT_D + kt * 32 + kg * 8;
                const f4u p0 = *(const f4u*)(src);
                const f4u p1 = *(const f4u*)(src + 4);
#pragma unroll
                for (int e = 0; e < 4; ++e) {
                    av[e]     = (short)f2bf(wt * p0.v[e]);
                    av[e + 4] = (short)f2bf(wt * p1.v[e]);
                }
            }
            a[kt] = av;
        }
    }

    for (int nt = wave; nt < NMT; nt += 4) {
        f32x4 acc = (f32x4){0.f, 0.f, 0.f, 0.f};
#pragma unroll
        for (int kt = 0; kt < NKTC; ++kt)
            acc = __builtin_amdgcn_mfma_f32_16x16x32_bf16(
                a[kt], bp[(kt * NMT + nt) * 64 + lane], acc, 0, 0, 0);
        const int i_loc = nt * 16 + col;
        if (!s_flag[i_loc]) continue;
        const int c  = i_loc >= WPAD, wi = i_loc - c * WPAD;
        const int f  = f0 + wi;
        const int ch = f >> 7, df = f & 127;   // CHUNK = 128
        const int lo = (ch << 7) - WPAD;
        const size_t colIdx = (size_t)(c * CHUNK + df);
#pragma unroll
        for (int reg = 0; reg < 4; ++reg) {
            const int j_loc = mt * 16 + kg * 4 + reg;
            if (!s_flag[j_loc]) continue;
            const int c2 = j_loc >= WPAD, wi2 = j_loc - c2 * WPAD;
            const int jj = f0 + wi2 - lo;      // in [1, 350]
            atomicAdd(Mf + ((size_t)ch * K2 + c2 * WIN + jj) * OC + colIdx,
                      acc[reg]);
        }
    }
}

// ---- convert banded Mf32 -> bf16 B-frags: (chunk, kt, ct, lane, 8)
__global__ __launch_bounds__(256) void bs_mk_bf16(
    const float* __restrict__ Mf, unsigned short* __restrict__ Mb)
{
    const int chunk = blockIdx.x, kt = blockIdx.y;
    for (int q = threadIdx.x; q < NCT * 64; q += 256) {
        const int ct = q >> 6, lane = q & 63;
        const int col = lane & 15, kg = lane >> 4;
        unsigned short v[8];
#pragma unroll
        for (int e = 0; e < 8; ++e) {
            const int jp = kt * 32 + kg * 8 + e;
            v[e] = f2bf(Mf[((size_t)chunk * K2 + jp) * OC + ct * 16 + col]);
        }
        st8(Mb + ((((size_t)chunk * KT2 + kt) * NCT + ct) * 64 + lane) * 8, v);
    }
}

// ---- main: blocked banded GEMM. BM=128 x BN=256, 8 waves (2Mx4N),
// A double-buffered in LDS (one barrier + 16 MFMA/wave per phase),
// B loaded per-phase from L2-resident Mb. 22 unrolled phases.
__global__ __launch_bounds__(512) void bs_banded(
    const unsigned short* __restrict__ x_bf,
    const unsigned short* __restrict__ Mb,
    const float* __restrict__ bias_g, float* __restrict__ out)
{
    __shared__ unsigned short s_a[2][BM][SALD];   // 18,432 B

    const int chunk  = blockIdx.y;                // t-tile fastest
    const int m_base = blockIdx.x * BM;
    const int tid    = threadIdx.x;
    const int lo     = chunk * CHUNK - WPAD;      // f-space window start

    const int lane = tid & 63, wave = tid >> 6;   // 8 waves
    const int col  = lane & 15, kg  = lane >> 4;
    const int wr64 = (wave >> 2) * 64;            // wave m-origin
    const int wc4  = (wave & 3) * 4;              // wave n-origin (ct units)
    const int kgs  = kg * 8;

    const int b  = m_base >> 10;                  // block stays in one b
    const int t0 = m_base & 1023;

    // staging role: thread -> (row, k-subchunk)
    const int r_st = tid >> 2;                    // 0..127
    const int ks8  = (tid & 3) * 8;               // 0,8,16,24 shorts
    const unsigned short* p0 = x_bf
        + ((size_t)(b * 2 + 0) * T_DIM + t0 + r_st) * XP + lo + ks8;
    const unsigned short* p1 = x_bf
        + ((size_t)(b * 2 + 1) * T_DIM + t0 + r_st) * XP + lo + ks8;
    // edge/pad granules read finite neighbor/slack bytes that multiply
    // compose's zero K-rows (chunk 0: >= x_bf-224B inside Mb; chunk 8:
    // <= +464B past x_bf, inside ws slack; 0xAA / f2bf bytes are finite bf16).

    const bf16x8* bp = (const bf16x8*)(Mb + (size_t)chunk * KT2 * NCT * 512);

    f32x4 acc[4][4];
#pragma unroll
    for (int mf = 0; mf < 4; ++mf)
#pragma unroll
        for (int nf = 0; nf < 4; ++nf) acc[mf][nf] = (f32x4){0.f, 0.f, 0.f, 0.f};

    // prologue: stage kt = 0 into buf 0
    {
        const bf16x8 v = *(const bf16x8*)(p0);
        *(bf16x8*)&s_a[0][r_st][ks8] = v;
    }
    __syncthreads();

#define PH(KT)                                                                 \
    {                                                                          \
        bf16x8 nxt;                                                            \
        if ((KT) + 1 < KT2)                                                    \
            nxt = *(const bf16x8*)(((((KT) + 1) >= 11) ? p1 : p0)              \
                    + (((KT) + 1) * 32 - (((KT) + 1) >= 11) * 352));           \
        bf16x8 af[4];                                                          \
        _Pragma("unroll")                                                      \
        for (int mf = 0; mf < 4; ++mf)                                         \
            af[mf] = *(const bf16x8*)&s_a[(KT) & 1][wr64 + mf * 16 + col][kgs];\
        bf16x8 bfr[4];                                                         \
        _Pragma("unroll")                                                      \
        for (int nf = 0; nf < 4; ++nf)                                         \
            bfr[nf] = bp[((size_t)(KT) * NCT + wc4 + nf) * 64 + lane];         \
        _Pragma("unroll")                                                      \
        for (int mf = 0; mf < 4; ++mf)                                         \
            _Pragma("unroll")                                                  \
            for (int nf = 0; nf < 4; ++nf)                                     \
                acc[mf][nf] = __builtin_amdgcn_mfma_f32_16x16x32_bf16(         \
                    af[mf], bfr[nf], acc[mf][nf], 0, 0, 0);                    \
        if ((KT) + 1 < KT2) {                                                  \
            *(bf16x8*)&s_a[((KT) + 1) & 1][r_st][ks8] = nxt;                   \
            __syncthreads();                                                   \
        }                                                                      \
    }

    PH(0)  PH(1)  PH(2)  PH(3)  PH(4)  PH(5)  PH(6)  PH(7)
    PH(8)  PH(9)  PH(10) PH(11) PH(12) PH(13) PH(14) PH(15)
    PH(16) PH(17) PH(18) PH(19) PH(20) PH(21)
#undef PH

    // epilogue: dense store + bias
#pragma unroll
    for (int nf = 0; nf < 4; ++nf) {
        const int i  = (wc4 + nf) * 16 + col;     // [0, 256)
        const int c  = i >> 7, df = i & 127;
        const int f  = chunk * CHUNK + df;
        if (f >= F_DIM) continue;
        const float bv = bias_g[c * F_DIM + f];
#pragma unroll
        for (int mf = 0; mf < 4; ++mf) {
            float* orow = out
                + ((size_t)(b * 2 + c) * T_DIM + t0 + wr64 + mf * 16 + kg * 4)
                  * F_DIM + f;
#pragma unroll
            for (int reg = 0; reg < 4; ++reg)
                orow[(size_t)reg * F_DIM] = acc[mf][nf][reg] + bv;
        }
    }
}

extern "C" void kernel_launch(void* const* d_in, const int* in_sizes, int n_in,
                              void* d_out, int out_size, void* d_ws, size_t ws_size,
                              hipStream_t stream) {
    const float* x      = (const float*)d_in[0];
    const float* pre_w  = (const float*)d_in[1];
    const float* pre_b  = (const float*)d_in[2];
    const float* post_w = (const float*)d_in[3];
    const float* post_b = (const float*)d_in[4];
    const int*   idx    = (const int*)d_in[5];
    const float* melw   = (const float*)d_in[6];
    const float* mask   = (const float*)d_in[7];
    const float* ola    = (const float*)d_in[8];
    float* out = (float*)d_out;

    const int W   = in_sizes[5] / K_BANDS;   // <= 112
    const int din = 2 * W;

    // workspace: Mf | bias | postP | Mb | x_bf | slack   (~30.3 MB)
    const size_t mf_bytes   = (size_t)NCHUNK * K2 * OC * 4;          // 6,488,064
    const size_t bias_bytes = 8448;
    float*          Mf     = (float*)d_ws;
    float*          bias_g = (float*)((char*)d_ws + mf_bytes);
    unsigned short* postP  = (unsigned short*)((char*)d_ws + mf_bytes + bias_bytes);
    const size_t frag_bytes = (size_t)K_BANDS * NKTC * NMT * 64 * 8 * 2; // 3,670,016
    unsigned short* Mb     = (unsigned short*)((char*)postP + frag_bytes);
    const size_t mb_bytes   = (size_t)NCHUNK * KT2 * NCT * 64 * 8 * 2;   // 3,244,032
    unsigned short* x_bf   = (unsigned short*)((char*)Mb + mb_bytes);

    const int zcount = (int)((mf_bytes + bias_bytes) / 4);

    bs_cvt<<<B_DIM * 2 * T_DIM, 256, 0, stream>>>(x, x_bf, (float*)d_ws, zcount);
    bs_prep<<<dim3(K_BANDS, NKTC), 256, 0, stream>>>(
        post_w, idx, melw, mask, ola, postP, W, din);
    bs_compose<<<dim3(K_BANDS, NMT + 1), 256, 0, stream>>>(
        postP, pre_w, pre_b, post_w, post_b, idx, melw, mask, ola,
        Mf, bias_g, W, din);
    bs_mk_bf16<<<dim3(NCHUNK, KT2), 256, 0, stream>>>(Mf, Mb);

    bs_banded<<<dim3((B_DIM * T_DIM) / BM, NCHUNK), 512, 0, stream>>>(
        x_bf, Mb, bias_g, out);
}

// Round 22
// 69.023 us; speedup vs baseline: 1.1122x; 1.1122x over previous
//
#include <hip/hip_runtime.h>

// BandSplit R22 = R20 (measured best 69.3us, twice) + bs_cvt/bs_prep fused
// into one front kernel (independent outputs; saves one launch).
// Pipeline: bs_front (x->bf16 pad + zero Mf/bias + post' frags) |
// bs_compose (banded M + bias) | bs_mk_bf16 | bs_banded (banded GEMM).

#define K_BANDS 64
#define COUT_D  128
#define T_DIM   1024
#define B_DIM   4
#define F_DIM   1025
#define XP      1032     // padded bf16 x row length ([1025,1032) zeroed)
#define WPAD    112      // padded band width (W <= 112, verified R2-R21)
#define DINP    224      // 2*WPAD, channel-blocked j/i = c*112 + wi
#define NMT     14       // DINP/16 tiles (compose geometry)
#define NKTC    4        // 128/32 compose-K tiles
#define CHUNK   128      // output f-bins per chunk
#define NCHUNK  9        // ceil(1025/128)
#define WIN     352      // 112 + 128 + 112 input window
#define K2      704      // 2*WIN
#define KT2     22       // K2/32
#define OC      256      // out cols per chunk (2ch x 128)
#define NCT     16       // OC/16
#define M_TILE  32       // rows per main block
#define SXLD    712      // s_x row stride (shorts): 356 dw %32=4 -> spread
#define NCVT    (B_DIM * 2 * T_DIM)   // 8192 cvt blocks

typedef __attribute__((ext_vector_type(8))) short bf16x8;
typedef __attribute__((ext_vector_type(4))) float f32x4;

__device__ __forceinline__ unsigned short f2bf(float f) {
    unsigned u = __builtin_bit_cast(unsigned, f);
    u += 0x7FFFu + ((u >> 16) & 1u);          // RNE
    return (unsigned short)(u >> 16);
}
__device__ __forceinline__ void st8(unsigned short* o, const unsigned short* v) {
    *(ushort4*)(o)     = make_ushort4(v[0], v[1], v[2], v[3]);
    *(ushort4*)(o + 4) = make_ushort4(v[4], v[5], v[6], v[7]);
}

struct alignas(4) f4u { float v[4]; };        // dword-aligned 16B load

// ---- front: blocks [0,8192) = cvt (x -> padded bf16) + zero Mf/bias;
//             blocks [8192, 8192+256) = pack post' B-frags.
__global__ __launch_bounds__(256) void bs_front(
    const float* __restrict__ x, unsigned short* __restrict__ x_bf,
    float* __restrict__ zbase, int zcount,
    const float* __restrict__ post_w, const int* __restrict__ idx,
    const float* __restrict__ melw, const float* __restrict__ mask,
    const float* __restrict__ ola, unsigned short* __restrict__ dstB,
    int W, int din)
{
    const int bid = blockIdx.x;
    const int tid = threadIdx.x;

    if (bid < NCVT) {
        const int row = bid;                  // (b*2+c)*1024 + t
        {
            const int i = bid * 256 + tid;
            if (i < zcount) zbase[i] = 0.f;
        }
        const float* src = x + (size_t)row * F_DIM;
        unsigned short* dst = x_bf + (size_t)row * XP;
        for (int p = tid; p < XP / 4; p += 256) {
            const int f = 4 * p;
            unsigned short v[4];
            if (f + 4 <= F_DIM) {
                const f4u vv = *reinterpret_cast<const f4u*>(src + f);
#pragma unroll
                for (int e = 0; e < 4; ++e) v[e] = f2bf(vv.v[e]);
            } else {
#pragma unroll
                for (int e = 0; e < 4; ++e)
                    v[e] = (f + e < F_DIM) ? f2bf(src[f + e]) : (unsigned short)0;
            }
            *(ushort4*)(dst + f) = make_ushort4(v[0], v[1], v[2], v[3]);
        }
        return;
    }

    // prep part: 256 blocks -> (k, kt)
    const int pb = bid - NCVT;
    const int k  = pb >> 2;
    const int kt = pb & 3;
    for (int q = tid; q < NMT * 64; q += 256) {
        const int ct = q >> 6, lane = q & 63;
        const int col = lane & 15, kg = lane >> 4;
        const int i  = ct * 16 + col;
        const int cc = (i >= WPAD);
        const int wi = i - cc * WPAD;
        float sc = 0.f;
        if (wi < W) {
            const float mw = melw[k * W + wi] * mask[k * W + wi];
            if (mw != 0.f) sc = 1.0f / ola[idx[k * W + wi]];
        }
        unsigned short v[8];
#pragma unroll
        for (int e = 0; e < 8; ++e) {
            const int o = kt * 32 + kg * 8 + e;
            const float f = (sc != 0.f)
                ? sc * post_w[((size_t)k * COUT_D + o) * din + 2 * wi + cc] : 0.f;
            v[e] = f2bf(f);
        }
        st8(dstB + ((((size_t)k * NKTC + kt) * NMT + ct) * 64 + lane) * 8, v);
    }
}

// ---- compose A_k = pre'^T x post', atomicAdd into banded Mf.
// A-frags built on the fly.  mt in [0,14): compose; mt == 14: bias.
__global__ __launch_bounds__(256) void bs_compose(
    const unsigned short* __restrict__ postP,
    const float* __restrict__ pre_w,  const float* __restrict__ pre_b,
    const float* __restrict__ post_w, const float* __restrict__ post_b,
    const int* __restrict__ idx, const float* __restrict__ melw,
    const float* __restrict__ mask, const float* __restrict__ ola,
    float* __restrict__ Mf, float* __restrict__ bias_g, int W, int din)
{
    __shared__ unsigned char s_flag[DINP];
    const int k   = blockIdx.x;
    const int mt  = blockIdx.y;
    const int tid = threadIdx.x;
    const int f0  = idx[(size_t)k * W];

    if (mt == NMT) {          // bias block
        if (tid >= DINP) return;
        const int c = tid >= WPAD, wi = tid - c * WPAD;
        if (wi >= W) return;
        if (melw[k * W + wi] * mask[k * W + wi] == 0.f) return;
        const int f = idx[k * W + wi];
        float v = post_b[(size_t)k * din + 2 * wi + c];
        for (int o = 0; o < COUT_D; ++o)
            v += pre_b[k * COUT_D + o]
                 * post_w[((size_t)k * COUT_D + o) * din + 2 * wi + c];
        atomicAdd(bias_g + c * F_DIM + f, v / ola[f]);
        return;
    }

    if (tid < DINP) {
        const int cc = tid >= WPAD, wi = tid - cc * WPAD;
        s_flag[tid] = (wi < W) && (melw[k * W + wi] * mask[k * W + wi] != 0.f);
    }
    __syncthreads();

    const int lane = tid & 63, wave = tid >> 6;
    const int col  = lane & 15, kg  = lane >> 4;
    const bf16x8* bp = (const bf16x8*)(postP + (size_t)k * NKTC * NMT * 512);

    bf16x8 a[NKTC];
    {
        const int jl  = mt * 16 + col;
        const int cc2 = jl >= WPAD, wj = jl - cc2 * WPAD;
        float wt = 0.f;
        if (wj < W) wt = melw[k * W + wj] * mask[k * W + wj];
#pragma unroll
        for (int kt = 0; kt < NKTC; ++kt) {
            bf16x8 av = (bf16x8){0, 0, 0, 0, 0, 0, 0, 0};
            if (wt != 0.f) {
                const float* src = pre_w
                    + ((size_t)k * din + 2 * wj + cc2) * COUT_D + kt * 32 + kg * 8;
                const f4u p0 = *(const f4u*)(src);
                const f4u p1 = *(const f4u*)(src + 4);
#pragma unroll
                for (int e = 0; e < 4; ++e) {
                    av[e]     = (short)f2bf(wt * p0.v[e]);
                    av[e + 4] = (short)f2bf(wt * p1.v[e]);
                }
            }
            a[kt] = av;
        }
    }

    for (int nt = wave; nt < NMT; nt += 4) {
        f32x4 acc = (f32x4){0.f, 0.f, 0.f, 0.f};
#pragma unroll
        for (int kt = 0; kt < NKTC; ++kt)
            acc = __builtin_amdgcn_mfma_f32_16x16x32_bf16(
                a[kt], bp[(kt * NMT + nt) * 64 + lane], acc, 0, 0, 0);
        const int i_loc = nt * 16 + col;
        if (!s_flag[i_loc]) continue;
        const int c  = i_loc >= WPAD, wi = i_loc - c * WPAD;
        const int f  = f0 + wi;
        const int ch = f >> 7, df = f & 127;   // CHUNK = 128
        const int lo = (ch << 7) - WPAD;
        const size_t colIdx = (size_t)(c * CHUNK + df);
#pragma unroll
        for (int reg = 0; reg < 4; ++reg) {
            const int j_loc = mt * 16 + kg * 4 + reg;
            if (!s_flag[j_loc]) continue;
            const int c2 = j_loc >= WPAD, wi2 = j_loc - c2 * WPAD;
            const int jj = f0 + wi2 - lo;      // in [1, 350]
            atomicAdd(Mf + ((size_t)ch * K2 + c2 * WIN + jj) * OC + colIdx,
                      acc[reg]);
        }
    }
}

// ---- convert banded Mf32 -> bf16 B-frags: (chunk, kt, ct, lane, 8)
__global__ __launch_bounds__(256) void bs_mk_bf16(
    const float* __restrict__ Mf, unsigned short* __restrict__ Mb)
{
    const int chunk = blockIdx.x, kt = blockIdx.y;
    for (int q = threadIdx.x; q < NCT * 64; q += 256) {
        const int ct = q >> 6, lane = q & 63;
        const int col = lane & 15, kg = lane >> 4;
        unsigned short v[8];
#pragma unroll
        for (int e = 0; e < 8; ++e) {
            const int jp = kt * 32 + kg * 8 + e;
            v[e] = f2bf(Mf[((size_t)chunk * K2 + jp) * OC + ct * 16 + col]);
        }
        st8(Mb + ((((size_t)chunk * KT2 + kt) * NCT + ct) * 64 + lane) * 8, v);
    }
}

// ---- main: out_row = M . x_window + bias. Staging = aligned ushort8 copies
// from pre-converted x_bf (no f2bf, clamps only at edge chunks).
__global__ __launch_bounds__(1024) void bs_banded(
    const unsigned short* __restrict__ x_bf,
    const unsigned short* __restrict__ Mb,
    const float* __restrict__ bias_g, float* __restrict__ out)
{
    __shared__ unsigned short s_x[M_TILE][SXLD];

    const int chunk  = blockIdx.y;                // t-tile fastest
    const int m_base = blockIdx.x * M_TILE;
    const int tid    = threadIdx.x;
    const int lo     = chunk * CHUNK - WPAD;      // f-space window start

    // stage: 32 rows x 2 ch x 44 ushort8 chunks
    for (int p = tid; p < M_TILE * 2 * 44; p += 1024) {
        const int seg = p / 44, q = p - seg * 44;
        const int row = seg >> 1, c = seg & 1;
        const int m = m_base + row, b = m >> 10, t = m & 1023;
        const unsigned short* sr = x_bf + ((size_t)(b * 2 + c) * T_DIM + t) * XP;
        const int fl = lo + 8 * q;
        bf16x8 v;
        if (fl >= 0 && fl + 8 <= XP) {
            v = *(const bf16x8*)(sr + fl);        // 16B-aligned fast path
        } else {                                  // edge chunks: clamp addr
#pragma unroll
            for (int e = 0; e < 8; ++e) {
                const int f = min(max(fl + e, 0), F_DIM - 1);
                v[e] = (short)sr[f];
            }
        }
        *(bf16x8*)&s_x[row][c * WIN + 8 * q] = v;
    }
    __syncthreads();

    const int lane = tid & 63, wave = tid >> 6;   // wave in [0,16) = ct
    const int col  = lane & 15, kg  = lane >> 4;

    f32x4 acc[2];
#pragma unroll
    for (int mf = 0; mf < 2; ++mf) acc[mf] = (f32x4){0.f, 0.f, 0.f, 0.f};

    const bf16x8* bp = (const bf16x8*)(Mb + (size_t)chunk * KT2 * NCT * 512);

    bf16x8 b0, b1, b2, b3;
    b0 = bp[(size_t)(0 * NCT + wave) * 64 + lane];
    b1 = bp[(size_t)(1 * NCT + wave) * 64 + lane];
    b2 = bp[(size_t)(2 * NCT + wave) * 64 + lane];
    b3 = bp[(size_t)(3 * NCT + wave) * 64 + lane];

    bf16x8 aC0 = *(const bf16x8*)&s_x[col][kg * 8];
    bf16x8 aC1 = *(const bf16x8*)&s_x[16 + col][kg * 8];
    bf16x8 aN0, aN1;

#define PH(KT, BUF)                                                            \
    {                                                                          \
        if ((KT) + 1 < KT2) {                                                  \
            aN0 = *(const bf16x8*)&s_x[col][((KT) + 1) * 32 + kg * 8];         \
            aN1 = *(const bf16x8*)&s_x[16 + col][((KT) + 1) * 32 + kg * 8];    \
        }                                                                      \
        acc[0] = __builtin_amdgcn_mfma_f32_16x16x32_bf16(                      \
            aC0, BUF, acc[0], 0, 0, 0);                                        \
        acc[1] = __builtin_amdgcn_mfma_f32_16x16x32_bf16(                      \
            aC1, BUF, acc[1], 0, 0, 0);                                        \
        if ((KT) + 4 < KT2) {                                                  \
            BUF = bp[(size_t)(((KT) + 4) * NCT + wave) * 64 + lane];           \
        }                                                                      \
        aC0 = aN0; aC1 = aN1;                                                  \
    }

    PH(0, b0)  PH(1, b1)  PH(2, b2)  PH(3, b3)
    PH(4, b0)  PH(5, b1)  PH(6, b2)  PH(7, b3)
    PH(8, b0)  PH(9, b1)  PH(10, b2) PH(11, b3)
    PH(12, b0) PH(13, b1) PH(14, b2) PH(15, b3)
    PH(16, b0) PH(17, b1) PH(18, b2) PH(19, b3)
    PH(20, b0) PH(21, b1)
#undef PH

    // epilogue: dense store + bias
    const int b  = m_base >> 10;
    const int t0 = m_base & 1023;
    {
        const int i  = wave * 16 + col;
        const int c  = i >> 7, df = i & 127;
        const int f  = chunk * CHUNK + df;
        if (f < F_DIM) {
            const float bv = bias_g[c * F_DIM + f];
            float* orow = out + ((size_t)(b * 2 + c) * T_DIM + t0) * F_DIM + f;
#pragma unroll
            for (int mf = 0; mf < 2; ++mf)
#pragma unroll
                for (int reg = 0; reg < 4; ++reg) {
                    const int r = mf * 16 + kg * 4 + reg;
                    orow[(size_t)r * F_DIM] = acc[mf][reg] + bv;
                }
        }
    }
}

extern "C" void kernel_launch(void* const* d_in, const int* in_sizes, int n_in,
                              void* d_out, int out_size, void* d_ws, size_t ws_size,
                              hipStream_t stream) {
    const float* x      = (const float*)d_in[0];
    const float* pre_w  = (const float*)d_in[1];
    const float* pre_b  = (const float*)d_in[2];
    const float* post_w = (const float*)d_in[3];
    const float* post_b = (const float*)d_in[4];
    const int*   idx    = (const int*)d_in[5];
    const float* melw   = (const float*)d_in[6];
    const float* mask   = (const float*)d_in[7];
    const float* ola    = (const float*)d_in[8];
    float* out = (float*)d_out;

    const int W   = in_sizes[5] / K_BANDS;   // <= 112
    const int din = 2 * W;

    // workspace: Mf | bias | postP | Mb | x_bf   (~30.3 MB)
    const size_t mf_bytes   = (size_t)NCHUNK * K2 * OC * 4;          // 6,488,064
    const size_t bias_bytes = 8448;
    float*          Mf     = (float*)d_ws;
    float*          bias_g = (float*)((char*)d_ws + mf_bytes);
    unsigned short* postP  = (unsigned short*)((char*)d_ws + mf_bytes + bias_bytes);
    const size_t frag_bytes = (size_t)K_BANDS * NKTC * NMT * 64 * 8 * 2; // 3,670,016
    unsigned short* Mb     = (unsigned short*)((char*)postP + frag_bytes);
    const size_t mb_bytes   = (size_t)NCHUNK * KT2 * NCT * 64 * 8 * 2;   // 3,244,032
    unsigned short* x_bf   = (unsigned short*)((char*)Mb + mb_bytes);

    const int zcount = (int)((mf_bytes + bias_bytes) / 4);

    bs_front<<<NCVT + K_BANDS * NKTC, 256, 0, stream>>>(
        x, x_bf, (float*)d_ws, zcount,
        post_w, idx, melw, mask, ola, postP, W, din);
    bs_compose<<<dim3(K_BANDS, NMT + 1), 256, 0, stream>>>(
        postP, pre_w, pre_b, post_w, post_b, idx, melw, mask, ola,
        Mf, bias_g, W, din);
    bs_mk_bf16<<<dim3(NCHUNK, KT2), 256, 0, stream>>>(Mf, Mb);

    bs_banded<<<dim3((B_DIM * T_DIM) / M_TILE, NCHUNK), 1024, 0, stream>>>(
        x_bf, Mb, bias_g, out);
}

// Round 23
// 67.604 us; speedup vs baseline: 1.1356x; 1.0210x over previous
//
#include <hip/hip_runtime.h>

// BandSplit R23 = R22 with launch-level overlap: compose does NOT read x_bf,
// so cvt (memory-bound, 8192 blocks) and compose (latency-bound, 960 blocks)
// run in ONE dispatch (bs_mid, compose blocks first). Pipeline:
// bs_front (zero Mf/bias + post' frags) | bs_mid (compose+bias || cvt) |
// bs_mk_bf16 | bs_banded (unchanged, ~40us).

#define K_BANDS 64
#define COUT_D  128
#define T_DIM   1024
#define B_DIM   4
#define F_DIM   1025
#define XP      1032     // padded bf16 x row length ([1025,1032) zeroed)
#define WPAD    112      // padded band width (W <= 112, verified R2-R22)
#define DINP    224      // 2*WPAD, channel-blocked j/i = c*112 + wi
#define NMT     14       // DINP/16 tiles (compose geometry)
#define NKTC    4        // 128/32 compose-K tiles
#define CHUNK   128      // output f-bins per chunk
#define NCHUNK  9        // ceil(1025/128)
#define WIN     352      // 112 + 128 + 112 input window
#define K2      704      // 2*WIN
#define KT2     22       // K2/32
#define OC      256      // out cols per chunk (2ch x 128)
#define NCT     16       // OC/16
#define M_TILE  32       // rows per main block
#define SXLD    712      // s_x row stride (shorts): 356 dw %32=4 -> spread
#define NCVT    (B_DIM * 2 * T_DIM)      // 8192 cvt rows
#define NCOMP   (K_BANDS * (NMT + 1))    // 960 compose blocks (incl bias)

typedef __attribute__((ext_vector_type(8))) short bf16x8;
typedef __attribute__((ext_vector_type(4))) float f32x4;

__device__ __forceinline__ unsigned short f2bf(float f) {
    unsigned u = __builtin_bit_cast(unsigned, f);
    u += 0x7FFFu + ((u >> 16) & 1u);          // RNE
    return (unsigned short)(u >> 16);
}
__device__ __forceinline__ void st8(unsigned short* o, const unsigned short* v) {
    *(ushort4*)(o)     = make_ushort4(v[0], v[1], v[2], v[3]);
    *(ushort4*)(o + 4) = make_ushort4(v[4], v[5], v[6], v[7]);
}

struct alignas(4) f4u { float v[4]; };        // dword-aligned 16B load

// ---- front: 256 blocks. Each zeroes a stripe of Mf/bias, then packs the
// post' B-frags for its (k, kt).
__global__ __launch_bounds__(256) void bs_front(
    const float* __restrict__ post_w, const int* __restrict__ idx,
    const float* __restrict__ melw, const float* __restrict__ mask,
    const float* __restrict__ ola, unsigned short* __restrict__ dstB,
    float* __restrict__ zbase, int zcount, int W, int din)
{
    const int bid = blockIdx.x;
    const int tid = threadIdx.x;
    for (int i = bid * 256 + tid; i < zcount; i += 256 * 256)
        zbase[i] = 0.f;

    const int k  = bid >> 2;
    const int kt = bid & 3;
    for (int q = tid; q < NMT * 64; q += 256) {
        const int ct = q >> 6, lane = q & 63;
        const int col = lane & 15, kg = lane >> 4;
        const int i  = ct * 16 + col;
        const int cc = (i >= WPAD);
        const int wi = i - cc * WPAD;
        float sc = 0.f;
        if (wi < W) {
            const float mw = melw[k * W + wi] * mask[k * W + wi];
            if (mw != 0.f) sc = 1.0f / ola[idx[k * W + wi]];
        }
        unsigned short v[8];
#pragma unroll
        for (int e = 0; e < 8; ++e) {
            const int o = kt * 32 + kg * 8 + e;
            const float f = (sc != 0.f)
                ? sc * post_w[((size_t)k * COUT_D + o) * din + 2 * wi + cc] : 0.f;
            v[e] = f2bf(f);
        }
        st8(dstB + ((((size_t)k * NKTC + kt) * NMT + ct) * 64 + lane) * 8, v);
    }
}

// ---- mid: blocks [0, NCOMP) = compose A_k + bias (atomicAdd into Mf/bias);
//           blocks [NCOMP, NCOMP+NCVT) = cvt x -> padded bf16 x_bf.
// compose never reads x_bf; cvt never touches Mf -- independent, co-scheduled.
__global__ __launch_bounds__(256) void bs_mid(
    const unsigned short* __restrict__ postP,
    const float* __restrict__ pre_w,  const float* __restrict__ pre_b,
    const float* __restrict__ post_w, const float* __restrict__ post_b,
    const int* __restrict__ idx, const float* __restrict__ melw,
    const float* __restrict__ mask, const float* __restrict__ ola,
    float* __restrict__ Mf, float* __restrict__ bias_g,
    const float* __restrict__ x, unsigned short* __restrict__ x_bf,
    int W, int din)
{
    __shared__ unsigned char s_flag[DINP];
    const int bid = blockIdx.x;
    const int tid = threadIdx.x;

    if (bid >= NCOMP) {                       // ---- cvt block
        const int row = bid - NCOMP;          // (b*2+c)*1024 + t
        const float* src = x + (size_t)row * F_DIM;
        unsigned short* dst = x_bf + (size_t)row * XP;
        for (int p = tid; p < XP / 4; p += 256) {
            const int f = 4 * p;
            unsigned short v[4];
            if (f + 4 <= F_DIM) {
                const f4u vv = *reinterpret_cast<const f4u*>(src + f);
#pragma unroll
                for (int e = 0; e < 4; ++e) v[e] = f2bf(vv.v[e]);
            } else {
#pragma unroll
                for (int e = 0; e < 4; ++e)
                    v[e] = (f + e < F_DIM) ? f2bf(src[f + e]) : (unsigned short)0;
            }
            *(ushort4*)(dst + f) = make_ushort4(v[0], v[1], v[2], v[3]);
        }
        return;
    }

    // ---- compose block
    const int k  = bid / (NMT + 1);
    const int mt = bid - k * (NMT + 1);
    const int f0 = idx[(size_t)k * W];

    if (mt == NMT) {          // bias block
        if (tid >= DINP) return;
        const int c = tid >= WPAD, wi = tid - c * WPAD;
        if (wi >= W) return;
        if (melw[k * W + wi] * mask[k * W + wi] == 0.f) return;
        const int f = idx[k * W + wi];
        float v = post_b[(size_t)k * din + 2 * wi + c];
        for (int o = 0; o < COUT_D; ++o)
            v += pre_b[k * COUT_D + o]
                 * post_w[((size_t)k * COUT_D + o) * din + 2 * wi + c];
        atomicAdd(bias_g + c * F_DIM + f, v / ola[f]);
        return;
    }

    if (tid < DINP) {
        const int cc = tid >= WPAD, wi = tid - cc * WPAD;
        s_flag[tid] = (wi < W) && (melw[k * W + wi] * mask[k * W + wi] != 0.f);
    }
    __syncthreads();

    const int lane = tid & 63, wave = tid >> 6;
    const int col  = lane & 15, kg  = lane >> 4;
    const bf16x8* bp = (const bf16x8*)(postP + (size_t)k * NKTC * NMT * 512);

    bf16x8 a[NKTC];
    {
        const int jl  = mt * 16 + col;
        const int cc2 = jl >= WPAD, wj = jl - cc2 * WPAD;
        float wt = 0.f;
        if (wj < W) wt = melw[k * W + wj] * mask[k * W + wj];
#pragma unroll
        for (int kt = 0; kt < NKTC; ++kt) {
            bf16x8 av = (bf16x8){0, 0, 0, 0, 0, 0, 0, 0};
            if (wt != 0.f) {
                const float* src = pre_w
                    + ((size_t)k * din + 2 * wj + cc2) * COUT_D + kt * 32 + kg * 8;
                const f4u p0 = *(const f4u*)(src);
                const f4u p1 = *(const f4u*)(src + 4);
#pragma unroll
                for (int e = 0; e < 4; ++e) {
                    av[e]     = (short)f2bf(wt * p0.v[e]);
                    av[e + 4] = (short)f2bf(wt * p1.v[e]);
                }
            }
            a[kt] = av;
        }
    }

    for (int nt = wave; nt < NMT; nt += 4) {
        f32x4 acc = (f32x4){0.f, 0.f, 0.f, 0.f};
#pragma unroll
        for (int kt = 0; kt < NKTC; ++kt)
            acc = __builtin_amdgcn_mfma_f32_16x16x32_bf16(
                a[kt], bp[(kt * NMT + nt) * 64 + lane], acc, 0, 0, 0);
        const int i_loc = nt * 16 + col;
        if (!s_flag[i_loc]) continue;
        const int c  = i_loc >= WPAD, wi = i_loc - c * WPAD;
        const int f  = f0 + wi;
        const int ch = f >> 7, df = f & 127;   // CHUNK = 128
        const int lo = (ch << 7) - WPAD;
        const size_t colIdx = (size_t)(c * CHUNK + df);
#pragma unroll
        for (int reg = 0; reg < 4; ++reg) {
            const int j_loc = mt * 16 + kg * 4 + reg;
            if (!s_flag[j_loc]) continue;
            const int c2 = j_loc >= WPAD, wi2 = j_loc - c2 * WPAD;
            const int jj = f0 + wi2 - lo;      // in [1, 350]
            atomicAdd(Mf + ((size_t)ch * K2 + c2 * WIN + jj) * OC + colIdx,
                      acc[reg]);
        }
    }
}

// ---- convert banded Mf32 -> bf16 B-frags: (chunk, kt, ct, lane, 8)
__global__ __launch_bounds__(256) void bs_mk_bf16(
    const float* __restrict__ Mf, unsigned short* __restrict__ Mb)
{
    const int chunk = blockIdx.x, kt = blockIdx.y;
    for (int q = threadIdx.x; q < NCT * 64; q += 256) {
        const int ct = q >> 6, lane = q & 63;
        const int col = lane & 15, kg = lane >> 4;
        unsigned short v[8];
#pragma unroll
        for (int e = 0; e < 8; ++e) {
            const int jp = kt * 32 + kg * 8 + e;
            v[e] = f2bf(Mf[((size_t)chunk * K2 + jp) * OC + ct * 16 + col]);
        }
        st8(Mb + ((((size_t)chunk * KT2 + kt) * NCT + ct) * 64 + lane) * 8, v);
    }
}

// ---- main: out_row = M . x_window + bias. Staging = aligned ushort8 copies
// from pre-converted x_bf (no f2bf, clamps only at edge chunks).
__global__ __launch_bounds__(1024) void bs_banded(
    const unsigned short* __restrict__ x_bf,
    const unsigned short* __restrict__ Mb,
    const float* __restrict__ bias_g, float* __restrict__ out)
{
    __shared__ unsigned short s_x[M_TILE][SXLD];

    const int chunk  = blockIdx.y;                // t-tile fastest
    const int m_base = blockIdx.x * M_TILE;
    const int tid    = threadIdx.x;
    const int lo     = chunk * CHUNK - WPAD;      // f-space window start

    // stage: 32 rows x 2 ch x 44 ushort8 chunks
    for (int p = tid; p < M_TILE * 2 * 44; p += 1024) {
        const int seg = p / 44, q = p - seg * 44;
        const int row = seg >> 1, c = seg & 1;
        const int m = m_base + row, b = m >> 10, t = m & 1023;
        const unsigned short* sr = x_bf + ((size_t)(b * 2 + c) * T_DIM + t) * XP;
        const int fl = lo + 8 * q;
        bf16x8 v;
        if (fl >= 0 && fl + 8 <= XP) {
            v = *(const bf16x8*)(sr + fl);        // 16B-aligned fast path
        } else {                                  // edge chunks: clamp addr
#pragma unroll
            for (int e = 0; e < 8; ++e) {
                const int f = min(max(fl + e, 0), F_DIM - 1);
                v[e] = (short)sr[f];
            }
        }
        *(bf16x8*)&s_x[row][c * WIN + 8 * q] = v;
    }
    __syncthreads();

    const int lane = tid & 63, wave = tid >> 6;   // wave in [0,16) = ct
    const int col  = lane & 15, kg  = lane >> 4;

    f32x4 acc[2];
#pragma unroll
    for (int mf = 0; mf < 2; ++mf) acc[mf] = (f32x4){0.f, 0.f, 0.f, 0.f};

    const bf16x8* bp = (const bf16x8*)(Mb + (size_t)chunk * KT2 * NCT * 512);

    bf16x8 b0, b1, b2, b3;
    b0 = bp[(size_t)(0 * NCT + wave) * 64 + lane];
    b1 = bp[(size_t)(1 * NCT + wave) * 64 + lane];
    b2 = bp[(size_t)(2 * NCT + wave) * 64 + lane];
    b3 = bp[(size_t)(3 * NCT + wave) * 64 + lane];

    bf16x8 aC0 = *(const bf16x8*)&s_x[col][kg * 8];
    bf16x8 aC1 = *(const bf16x8*)&s_x[16 + col][kg * 8];
    bf16x8 aN0, aN1;

#define PH(KT, BUF)                                                            \
    {                                                                          \
        if ((KT) + 1 < KT2) {                                                  \
            aN0 = *(const bf16x8*)&s_x[col][((KT) + 1) * 32 + kg * 8];         \
            aN1 = *(const bf16x8*)&s_x[16 + col][((KT) + 1) * 32 + kg * 8];    \
        }                                                                      \
        acc[0] = __builtin_amdgcn_mfma_f32_16x16x32_bf16(                      \
            aC0, BUF, acc[0], 0, 0, 0);                                        \
        acc[1] = __builtin_amdgcn_mfma_f32_16x16x32_bf16(                      \
            aC1, BUF, acc[1], 0, 0, 0);                                        \
        if ((KT) + 4 < KT2) {                                                  \
            BUF = bp[(size_t)(((KT) + 4) * NCT + wave) * 64 + lane];           \
        }                                                                      \
        aC0 = aN0; aC1 = aN1;                                                  \
    }

    PH(0, b0)  PH(1, b1)  PH(2, b2)  PH(3, b3)
    PH(4, b0)  PH(5, b1)  PH(6, b2)  PH(7, b3)
    PH(8, b0)  PH(9, b1)  PH(10, b2) PH(11, b3)
    PH(12, b0) PH(13, b1) PH(14, b2) PH(15, b3)
    PH(16, b0) PH(17, b1) PH(18, b2) PH(19, b3)
    PH(20, b0) PH(21, b1)
#undef PH

    // epilogue: dense store + bias
    const int b  = m_base >> 10;
    const int t0 = m_base & 1023;
    {
        const int i  = wave * 16 + col;
        const int c  = i >> 7, df = i & 127;
        const int f  = chunk * CHUNK + df;
        if (f < F_DIM) {
            const float bv = bias_g[c * F_DIM + f];
            float* orow = out + ((size_t)(b * 2 + c) * T_DIM + t0) * F_DIM + f;
#pragma unroll
            for (int mf = 0; mf < 2; ++mf)
#pragma unroll
                for (int reg = 0; reg < 4; ++reg) {
                    const int r = mf * 16 + kg * 4 + reg;
                    orow[(size_t)r * F_DIM] = acc[mf][reg] + bv;
                }
        }
    }
}

extern "C" void kernel_launch(void* const* d_in, const int* in_sizes, int n_in,
                              void* d_out, int out_size, void* d_ws, size_t ws_size,
                              hipStream_t stream) {
    const float* x      = (const float*)d_in[0];
    const float* pre_w  = (const float*)d_in[1];
    const float* pre_b  = (const float*)d_in[2];
    const float* post_w = (const float*)d_in[3];
    const float* post_b = (const float*)d_in[4];
    const int*   idx    = (const int*)d_in[5];
    const float* melw   = (const float*)d_in[6];
    const float* mask   = (const float*)d_in[7];
    const float* ola    = (const float*)d_in[8];
    float* out = (float*)d_out;

    const int W   = in_sizes[5] / K_BANDS;   // <= 112
    const int din = 2 * W;

    // workspace: Mf | bias | postP | Mb | x_bf   (~30.3 MB)
    const size_t mf_bytes   = (size_t)NCHUNK * K2 * OC * 4;          // 6,488,064
    const size_t bias_bytes = 8448;
    float*          Mf     = (float*)d_ws;
    float*          bias_g = (float*)((char*)d_ws + mf_bytes);
    unsigned short* postP  = (unsigned short*)((char*)d_ws + mf_bytes + bias_bytes);
    const size_t frag_bytes = (size_t)K_BANDS * NKTC * NMT * 64 * 8 * 2; // 3,670,016
    unsigned short* Mb     = (unsigned short*)((char*)postP + frag_bytes);
    const size_t mb_bytes   = (size_t)NCHUNK * KT2 * NCT * 64 * 8 * 2;   // 3,244,032
    unsigned short* x_bf   = (unsigned short*)((char*)Mb + mb_bytes);

    const int zcount = (int)((mf_bytes + bias_bytes) / 4);

    bs_front<<<K_BANDS * NKTC, 256, 0, stream>>>(
        post_w, idx, melw, mask, ola, postP, (float*)d_ws, zcount, W, din);
    bs_mid<<<NCOMP + NCVT, 256, 0, stream>>>(
        postP, pre_w, pre_b, post_w, post_b, idx, melw, mask, ola,
        Mf, bias_g, x, x_bf, W, din);
    bs_mk_bf16<<<dim3(NCHUNK, KT2), 256, 0, stream>>>(Mf, Mb);

    bs_banded<<<dim3((B_DIM * T_DIM) / M_TILE, NCHUNK), 1024, 0, stream>>>(
        x_bf, Mb, bias_g, out);
}

// Round 24
// 67.469 us; speedup vs baseline: 1.1379x; 1.0020x over previous
//
#include <hip/hip_runtime.h>

// BandSplit R24 = R23 + XCD-aware blockIdx.x swizzle on bs_banded (T1):
// 128 t-tiles % 8 XCDs == 0 -> bijective chunked remap; each XCD keeps a
// stable L2 working set (its t-span of x_bf + the chunk's Mb panel).
// Pipeline: bs_front (zero Mf/bias + post' frags) | bs_mid (compose || cvt) |
// bs_mk_bf16 | bs_banded.

#define K_BANDS 64
#define COUT_D  128
#define T_DIM   1024
#define B_DIM   4
#define F_DIM   1025
#define XP      1032     // padded bf16 x row length ([1025,1032) zeroed)
#define WPAD    112      // padded band width (W <= 112, verified R2-R23)
#define DINP    224      // 2*WPAD, channel-blocked j/i = c*112 + wi
#define NMT     14       // DINP/16 tiles (compose geometry)
#define NKTC    4        // 128/32 compose-K tiles
#define CHUNK   128      // output f-bins per chunk
#define NCHUNK  9        // ceil(1025/128)
#define WIN     352      // 112 + 128 + 112 input window
#define K2      704      // 2*WIN
#define KT2     22       // K2/32
#define OC      256      // out cols per chunk (2ch x 128)
#define NCT     16       // OC/16
#define M_TILE  32       // rows per main block
#define SXLD    712      // s_x row stride (shorts): 356 dw %32=4 -> spread
#define NCVT    (B_DIM * 2 * T_DIM)      // 8192 cvt rows
#define NCOMP   (K_BANDS * (NMT + 1))    // 960 compose blocks (incl bias)
#define NXCD    8
#define NTT     ((B_DIM * T_DIM) / M_TILE)   // 128 t-tiles (128 % 8 == 0)

typedef __attribute__((ext_vector_type(8))) short bf16x8;
typedef __attribute__((ext_vector_type(4))) float f32x4;

__device__ __forceinline__ unsigned short f2bf(float f) {
    unsigned u = __builtin_bit_cast(unsigned, f);
    u += 0x7FFFu + ((u >> 16) & 1u);          // RNE
    return (unsigned short)(u >> 16);
}
__device__ __forceinline__ void st8(unsigned short* o, const unsigned short* v) {
    *(ushort4*)(o)     = make_ushort4(v[0], v[1], v[2], v[3]);
    *(ushort4*)(o + 4) = make_ushort4(v[4], v[5], v[6], v[7]);
}

struct alignas(4) f4u { float v[4]; };        // dword-aligned 16B load

// ---- front: 256 blocks. Each zeroes a stripe of Mf/bias, then packs the
// post' B-frags for its (k, kt).
__global__ __launch_bounds__(256) void bs_front(
    const float* __restrict__ post_w, const int* __restrict__ idx,
    const float* __restrict__ melw, const float* __restrict__ mask,
    const float* __restrict__ ola, unsigned short* __restrict__ dstB,
    float* __restrict__ zbase, int zcount, int W, int din)
{
    const int bid = blockIdx.x;
    const int tid = threadIdx.x;
    for (int i = bid * 256 + tid; i < zcount; i += 256 * 256)
        zbase[i] = 0.f;

    const int k  = bid >> 2;
    const int kt = bid & 3;
    for (int q = tid; q < NMT * 64; q += 256) {
        const int ct = q >> 6, lane = q & 63;
        const int col = lane & 15, kg = lane >> 4;
        const int i  = ct * 16 + col;
        const int cc = (i >= WPAD);
        const int wi = i - cc * WPAD;
        float sc = 0.f;
        if (wi < W) {
            const float mw = melw[k * W + wi] * mask[k * W + wi];
            if (mw != 0.f) sc = 1.0f / ola[idx[k * W + wi]];
        }
        unsigned short v[8];
#pragma unroll
        for (int e = 0; e < 8; ++e) {
            const int o = kt * 32 + kg * 8 + e;
            const float f = (sc != 0.f)
                ? sc * post_w[((size_t)k * COUT_D + o) * din + 2 * wi + cc] : 0.f;
            v[e] = f2bf(f);
        }
        st8(dstB + ((((size_t)k * NKTC + kt) * NMT + ct) * 64 + lane) * 8, v);
    }
}

// ---- mid: blocks [0, NCOMP) = compose A_k + bias (atomicAdd into Mf/bias);
//           blocks [NCOMP, NCOMP+NCVT) = cvt x -> padded bf16 x_bf.
__global__ __launch_bounds__(256) void bs_mid(
    const unsigned short* __restrict__ postP,
    const float* __restrict__ pre_w,  const float* __restrict__ pre_b,
    const float* __restrict__ post_w, const float* __restrict__ post_b,
    const int* __restrict__ idx, const float* __restrict__ melw,
    const float* __restrict__ mask, const float* __restrict__ ola,
    float* __restrict__ Mf, float* __restrict__ bias_g,
    const float* __restrict__ x, unsigned short* __restrict__ x_bf,
    int W, int din)
{
    __shared__ unsigned char s_flag[DINP];
    const int bid = blockIdx.x;
    const int tid = threadIdx.x;

    if (bid >= NCOMP) {                       // ---- cvt block
        const int row = bid - NCOMP;          // (b*2+c)*1024 + t
        const float* src = x + (size_t)row * F_DIM;
        unsigned short* dst = x_bf + (size_t)row * XP;
        for (int p = tid; p < XP / 4; p += 256) {
            const int f = 4 * p;
            unsigned short v[4];
            if (f + 4 <= F_DIM) {
                const f4u vv = *reinterpret_cast<const f4u*>(src + f);
#pragma unroll
                for (int e = 0; e < 4; ++e) v[e] = f2bf(vv.v[e]);
            } else {
#pragma unroll
                for (int e = 0; e < 4; ++e)
                    v[e] = (f + e < F_DIM) ? f2bf(src[f + e]) : (unsigned short)0;
            }
            *(ushort4*)(dst + f) = make_ushort4(v[0], v[1], v[2], v[3]);
        }
        return;
    }

    // ---- compose block
    const int k  = bid / (NMT + 1);
    const int mt = bid - k * (NMT + 1);
    const int f0 = idx[(size_t)k * W];

    if (mt == NMT) {          // bias block
        if (tid >= DINP) return;
        const int c = tid >= WPAD, wi = tid - c * WPAD;
        if (wi >= W) return;
        if (melw[k * W + wi] * mask[k * W + wi] == 0.f) return;
        const int f = idx[k * W + wi];
        float v = post_b[(size_t)k * din + 2 * wi + c];
        for (int o = 0; o < COUT_D; ++o)
            v += pre_b[k * COUT_D + o]
                 * post_w[((size_t)k * COUT_D + o) * din + 2 * wi + c];
        atomicAdd(bias_g + c * F_DIM + f, v / ola[f]);
        return;
    }

    if (tid < DINP) {
        const int cc = tid >= WPAD, wi = tid - cc * WPAD;
        s_flag[tid] = (wi < W) && (melw[k * W + wi] * mask[k * W + wi] != 0.f);
    }
    __syncthreads();

    const int lane = tid & 63, wave = tid >> 6;
    const int col  = lane & 15, kg  = lane >> 4;
    const bf16x8* bp = (const bf16x8*)(postP + (size_t)k * NKTC * NMT * 512);

    bf16x8 a[NKTC];
    {
        const int jl  = mt * 16 + col;
        const int cc2 = jl >= WPAD, wj = jl - cc2 * WPAD;
        float wt = 0.f;
        if (wj < W) wt = melw[k * W + wj] * mask[k * W + wj];
#pragma unroll
        for (int kt = 0; kt < NKTC; ++kt) {
            bf16x8 av = (bf16x8){0, 0, 0, 0, 0, 0, 0, 0};
            if (wt != 0.f) {
                const float* src = pre_w
                    + ((size_t)k * din + 2 * wj + cc2) * COUT_D + kt * 32 + kg * 8;
                const f4u p0 = *(const f4u*)(src);
                const f4u p1 = *(const f4u*)(src + 4);
#pragma unroll
                for (int e = 0; e < 4; ++e) {
                    av[e]     = (short)f2bf(wt * p0.v[e]);
                    av[e + 4] = (short)f2bf(wt * p1.v[e]);
                }
            }
            a[kt] = av;
        }
    }

    for (int nt = wave; nt < NMT; nt += 4) {
        f32x4 acc = (f32x4){0.f, 0.f, 0.f, 0.f};
#pragma unroll
        for (int kt = 0; kt < NKTC; ++kt)
            acc = __builtin_amdgcn_mfma_f32_16x16x32_bf16(
                a[kt], bp[(kt * NMT + nt) * 64 + lane], acc, 0, 0, 0);
        const int i_loc = nt * 16 + col;
        if (!s_flag[i_loc]) continue;
        const int c  = i_loc >= WPAD, wi = i_loc - c * WPAD;
        const int f  = f0 + wi;
        const int ch = f >> 7, df = f & 127;   // CHUNK = 128
        const int lo = (ch << 7) - WPAD;
        const size_t colIdx = (size_t)(c * CHUNK + df);
#pragma unroll
        for (int reg = 0; reg < 4; ++reg) {
            const int j_loc = mt * 16 + kg * 4 + reg;
            if (!s_flag[j_loc]) continue;
            const int c2 = j_loc >= WPAD, wi2 = j_loc - c2 * WPAD;
            const int jj = f0 + wi2 - lo;      // in [1, 350]
            atomicAdd(Mf + ((size_t)ch * K2 + c2 * WIN + jj) * OC + colIdx,
                      acc[reg]);
        }
    }
}

// ---- convert banded Mf32 -> bf16 B-frags: (chunk, kt, ct, lane, 8)
__global__ __launch_bounds__(256) void bs_mk_bf16(
    const float* __restrict__ Mf, unsigned short* __restrict__ Mb)
{
    const int chunk = blockIdx.x, kt = blockIdx.y;
    for (int q = threadIdx.x; q < NCT * 64; q += 256) {
        const int ct = q >> 6, lane = q & 63;
        const int col = lane & 15, kg = lane >> 4;
        unsigned short v[8];
#pragma unroll
        for (int e = 0; e < 8; ++e) {
            const int jp = kt * 32 + kg * 8 + e;
            v[e] = f2bf(Mf[((size_t)chunk * K2 + jp) * OC + ct * 16 + col]);
        }
        st8(Mb + ((((size_t)chunk * KT2 + kt) * NCT + ct) * 64 + lane) * 8, v);
    }
}

// ---- main: out_row = M . x_window + bias, XCD-swizzled t-tile index.
__global__ __launch_bounds__(1024) void bs_banded(
    const unsigned short* __restrict__ x_bf,
    const unsigned short* __restrict__ Mb,
    const float* __restrict__ bias_g, float* __restrict__ out)
{
    __shared__ unsigned short s_x[M_TILE][SXLD];

    const int chunk = blockIdx.y;                 // t-tile fastest
    // T1 bijective chunked swizzle: 128 t-tiles, 8 XCDs, 16 per XCD
    const int tt     = (blockIdx.x % NXCD) * (NTT / NXCD) + blockIdx.x / NXCD;
    const int m_base = tt * M_TILE;
    const int tid    = threadIdx.x;
    const int lo     = chunk * CHUNK - WPAD;      // f-space window start

    // stage: 32 rows x 2 ch x 44 ushort8 chunks
    for (int p = tid; p < M_TILE * 2 * 44; p += 1024) {
        const int seg = p / 44, q = p - seg * 44;
        const int row = seg >> 1, c = seg & 1;
        const int m = m_base + row, b = m >> 10, t = m & 1023;
        const unsigned short* sr = x_bf + ((size_t)(b * 2 + c) * T_DIM + t) * XP;
        const int fl = lo + 8 * q;
        bf16x8 v;
        if (fl >= 0 && fl + 8 <= XP) {
            v = *(const bf16x8*)(sr + fl);        // 16B-aligned fast path
        } else {                                  // edge chunks: clamp addr
#pragma unroll
            for (int e = 0; e < 8; ++e) {
                const int f = min(max(fl + e, 0), F_DIM - 1);
                v[e] = (short)sr[f];
            }
        }
        *(bf16x8*)&s_x[row][c * WIN + 8 * q] = v;
    }
    __syncthreads();

    const int lane = tid & 63, wave = tid >> 6;   // wave in [0,16) = ct
    const int col  = lane & 15, kg  = lane >> 4;

    f32x4 acc[2];
#pragma unroll
    for (int mf = 0; mf < 2; ++mf) acc[mf] = (f32x4){0.f, 0.f, 0.f, 0.f};

    const bf16x8* bp = (const bf16x8*)(Mb + (size_t)chunk * KT2 * NCT * 512);

    bf16x8 b0, b1, b2, b3;
    b0 = bp[(size_t)(0 * NCT + wave) * 64 + lane];
    b1 = bp[(size_t)(1 * NCT + wave) * 64 + lane];
    b2 = bp[(size_t)(2 * NCT + wave) * 64 + lane];
    b3 = bp[(size_t)(3 * NCT + wave) * 64 + lane];

    bf16x8 aC0 = *(const bf16x8*)&s_x[col][kg * 8];
    bf16x8 aC1 = *(const bf16x8*)&s_x[16 + col][kg * 8];
    bf16x8 aN0, aN1;

#define PH(KT, BUF)                                                            \
    {                                                                          \
        if ((KT) + 1 < KT2) {                                                  \
            aN0 = *(const bf16x8*)&s_x[col][((KT) + 1) * 32 + kg * 8];         \
            aN1 = *(const bf16x8*)&s_x[16 + col][((KT) + 1) * 32 + kg * 8];    \
        }                                                                      \
        acc[0] = __builtin_amdgcn_mfma_f32_16x16x32_bf16(                      \
            aC0, BUF, acc[0], 0, 0, 0);                                        \
        acc[1] = __builtin_amdgcn_mfma_f32_16x16x32_bf16(                      \
            aC1, BUF, acc[1], 0, 0, 0);                                        \
        if ((KT) + 4 < KT2) {                                                  \
            BUF = bp[(size_t)(((KT) + 4) * NCT + wave) * 64 + lane];           \
        }                                                                      \
        aC0 = aN0; aC1 = aN1;                                                  \
    }

    PH(0, b0)  PH(1, b1)  PH(2, b2)  PH(3, b3)
    PH(4, b0)  PH(5, b1)  PH(6, b2)  PH(7, b3)
    PH(8, b0)  PH(9, b1)  PH(10, b2) PH(11, b3)
    PH(12, b0) PH(13, b1) PH(14, b2) PH(15, b3)
    PH(16, b0) PH(17, b1) PH(18, b2) PH(19, b3)
    PH(20, b0) PH(21, b1)
#undef PH

    // epilogue: dense store + bias
    const int b  = m_base >> 10;
    const int t0 = m_base & 1023;
    {
        const int i  = wave * 16 + col;
        const int c  = i >> 7, df = i & 127;
        const int f  = chunk * CHUNK + df;
        if (f < F_DIM) {
            const float bv = bias_g[c * F_DIM + f];
            float* orow = out + ((size_t)(b * 2 + c) * T_DIM + t0) * F_DIM + f;
#pragma unroll
            for (int mf = 0; mf < 2; ++mf)
#pragma unroll
                for (int reg = 0; reg < 4; ++reg) {
                    const int r = mf * 16 + kg * 4 + reg;
                    orow[(size_t)r * F_DIM] = acc[mf][reg] + bv;
                }
        }
    }
}

extern "C" void kernel_launch(void* const* d_in, const int* in_sizes, int n_in,
                              void* d_out, int out_size, void* d_ws, size_t ws_size,
                              hipStream_t stream) {
    const float* x      = (const float*)d_in[0];
    const float* pre_w  = (const float*)d_in[1];
    const float* pre_b  = (const float*)d_in[2];
    const float* post_w = (const float*)d_in[3];
    const float* post_b = (const float*)d_in[4];
    const int*   idx    = (const int*)d_in[5];
    const float* melw   = (const float*)d_in[6];
    const float* mask   = (const float*)d_in[7];
    const float* ola    = (const float*)d_in[8];
    float* out = (float*)d_out;

    const int W   = in_sizes[5] / K_BANDS;   // <= 112
    const int din = 2 * W;

    // workspace: Mf | bias | postP | Mb | x_bf   (~30.3 MB)
    const size_t mf_bytes   = (size_t)NCHUNK * K2 * OC * 4;          // 6,488,064
    const size_t bias_bytes = 8448;
    float*          Mf     = (float*)d_ws;
    float*          bias_g = (float*)((char*)d_ws + mf_bytes);
    unsigned short* postP  = (unsigned short*)((char*)d_ws + mf_bytes + bias_bytes);
    const size_t frag_bytes = (size_t)K_BANDS * NKTC * NMT * 64 * 8 * 2; // 3,670,016
    unsigned short* Mb     = (unsigned short*)((char*)postP + frag_bytes);
    const size_t mb_bytes   = (size_t)NCHUNK * KT2 * NCT * 64 * 8 * 2;   // 3,244,032
    unsigned short* x_bf   = (unsigned short*)((char*)Mb + mb_bytes);

    const int zcount = (int)((mf_bytes + bias_bytes) / 4);

    bs_front<<<K_BANDS * NKTC, 256, 0, stream>>>(
        post_w, idx, melw, mask, ola, postP, (float*)d_ws, zcount, W, din);
    bs_mid<<<NCOMP + NCVT, 256, 0, stream>>>(
        postP, pre_w, pre_b, post_w, post_b, idx, melw, mask, ola,
        Mf, bias_g, x, x_bf, W, din);
    bs_mk_bf16<<<dim3(NCHUNK, KT2), 256, 0, stream>>>(Mf, Mb);

    bs_banded<<<dim3(NTT, NCHUNK), 1024, 0, stream>>>(
        x_bf, Mb, bias_g, out);
}

// Round 25
// 66.984 us; speedup vs baseline: 1.1461x; 1.0072x over previous
//
#include <hip/hip_runtime.h>

// BandSplit FINAL (R24/R25 hold): banded-operator formulation.
// out_row = M . x_window + bias, where M = sum_k post'_k x pre'_k with
// melw/mask/(1/ola) folded (banded, half-width 112). 1406us baseline ->
// 67.5us. Pipeline: bs_front (zero Mf/bias + post' frags) |
// bs_mid (compose+bias || cvt x->bf16, co-dispatched: independent) |
// bs_mk_bf16 (Mf -> bf16 frags) | bs_banded (dense banded GEMM,
// M_TILE=32, 16 waves, depth-4 B-prefetch, XCD-swizzled t-tiles).

#define K_BANDS 64
#define COUT_D  128
#define T_DIM   1024
#define B_DIM   4
#define F_DIM   1025
#define XP      1032     // padded bf16 x row length ([1025,1032) zeroed)
#define WPAD    112      // padded band width (W <= 112, verified R2-R24)
#define DINP    224      // 2*WPAD, channel-blocked j/i = c*112 + wi
#define NMT     14       // DINP/16 tiles (compose geometry)
#define NKTC    4        // 128/32 compose-K tiles
#define CHUNK   128      // output f-bins per chunk
#define NCHUNK  9        // ceil(1025/128)
#define WIN     352      // 112 + 128 + 112 input window
#define K2      704      // 2*WIN
#define KT2     22       // K2/32
#define OC      256      // out cols per chunk (2ch x 128)
#define NCT     16       // OC/16
#define M_TILE  32       // rows per main block
#define SXLD    712      // s_x row stride (shorts): 356 dw %32=4 -> spread
#define NCVT    (B_DIM * 2 * T_DIM)      // 8192 cvt rows
#define NCOMP   (K_BANDS * (NMT + 1))    // 960 compose blocks (incl bias)
#define NXCD    8
#define NTT     ((B_DIM * T_DIM) / M_TILE)   // 128 t-tiles (128 % 8 == 0)

typedef __attribute__((ext_vector_type(8))) short bf16x8;
typedef __attribute__((ext_vector_type(4))) float f32x4;

__device__ __forceinline__ unsigned short f2bf(float f) {
    unsigned u = __builtin_bit_cast(unsigned, f);
    u += 0x7FFFu + ((u >> 16) & 1u);          // RNE
    return (unsigned short)(u >> 16);
}
__device__ __forceinline__ void st8(unsigned short* o, const unsigned short* v) {
    *(ushort4*)(o)     = make_ushort4(v[0], v[1], v[2], v[3]);
    *(ushort4*)(o + 4) = make_ushort4(v[4], v[5], v[6], v[7]);
}

struct alignas(4) f4u { float v[4]; };        // dword-aligned 16B load

// ---- front: 256 blocks. Each zeroes a stripe of Mf/bias, then packs the
// post' B-frags for its (k, kt).
__global__ __launch_bounds__(256) void bs_front(
    const float* __restrict__ post_w, const int* __restrict__ idx,
    const float* __restrict__ melw, const float* __restrict__ mask,
    const float* __restrict__ ola, unsigned short* __restrict__ dstB,
    float* __restrict__ zbase, int zcount, int W, int din)
{
    const int bid = blockIdx.x;
    const int tid = threadIdx.x;
    for (int i = bid * 256 + tid; i < zcount; i += 256 * 256)
        zbase[i] = 0.f;

    const int k  = bid >> 2;
    const int kt = bid & 3;
    for (int q = tid; q < NMT * 64; q += 256) {
        const int ct = q >> 6, lane = q & 63;
        const int col = lane & 15, kg = lane >> 4;
        const int i  = ct * 16 + col;
        const int cc = (i >= WPAD);
        const int wi = i - cc * WPAD;
        float sc = 0.f;
        if (wi < W) {
            const float mw = melw[k * W + wi] * mask[k * W + wi];
            if (mw != 0.f) sc = 1.0f / ola[idx[k * W + wi]];
        }
        unsigned short v[8];
#pragma unroll
        for (int e = 0; e < 8; ++e) {
            const int o = kt * 32 + kg * 8 + e;
            const float f = (sc != 0.f)
                ? sc * post_w[((size_t)k * COUT_D + o) * din + 2 * wi + cc] : 0.f;
            v[e] = f2bf(f);
        }
        st8(dstB + ((((size_t)k * NKTC + kt) * NMT + ct) * 64 + lane) * 8, v);
    }
}

// ---- mid: blocks [0, NCOMP) = compose A_k + bias (atomicAdd into Mf/bias);
//           blocks [NCOMP, NCOMP+NCVT) = cvt x -> padded bf16 x_bf.
// compose never reads x_bf; cvt never touches Mf -- independent, co-scheduled.
__global__ __launch_bounds__(256) void bs_mid(
    const unsigned short* __restrict__ postP,
    const float* __restrict__ pre_w,  const float* __restrict__ pre_b,
    const float* __restrict__ post_w, const float* __restrict__ post_b,
    const int* __restrict__ idx, const float* __restrict__ melw,
    const float* __restrict__ mask, const float* __restrict__ ola,
    float* __restrict__ Mf, float* __restrict__ bias_g,
    const float* __restrict__ x, unsigned short* __restrict__ x_bf,
    int W, int din)
{
    __shared__ unsigned char s_flag[DINP];
    const int bid = blockIdx.x;
    const int tid = threadIdx.x;

    if (bid >= NCOMP) {                       // ---- cvt block
        const int row = bid - NCOMP;          // (b*2+c)*1024 + t
        const float* src = x + (size_t)row * F_DIM;
        unsigned short* dst = x_bf + (size_t)row * XP;
        for (int p = tid; p < XP / 4; p += 256) {
            const int f = 4 * p;
            unsigned short v[4];
            if (f + 4 <= F_DIM) {
                const f4u vv = *reinterpret_cast<const f4u*>(src + f);
#pragma unroll
                for (int e = 0; e < 4; ++e) v[e] = f2bf(vv.v[e]);
            } else {
#pragma unroll
                for (int e = 0; e < 4; ++e)
                    v[e] = (f + e < F_DIM) ? f2bf(src[f + e]) : (unsigned short)0;
            }
            *(ushort4*)(dst + f) = make_ushort4(v[0], v[1], v[2], v[3]);
        }
        return;
    }

    // ---- compose block
    const int k  = bid / (NMT + 1);
    const int mt = bid - k * (NMT + 1);
    const int f0 = idx[(size_t)k * W];

    if (mt == NMT) {          // bias block
        if (tid >= DINP) return;
        const int c = tid >= WPAD, wi = tid - c * WPAD;
        if (wi >= W) return;
        if (melw[k * W + wi] * mask[k * W + wi] == 0.f) return;
        const int f = idx[k * W + wi];
        float v = post_b[(size_t)k * din + 2 * wi + c];
        for (int o = 0; o < COUT_D; ++o)
            v += pre_b[k * COUT_D + o]
                 * post_w[((size_t)k * COUT_D + o) * din + 2 * wi + c];
        atomicAdd(bias_g + c * F_DIM + f, v / ola[f]);
        return;
    }

    if (tid < DINP) {
        const int cc = tid >= WPAD, wi = tid - cc * WPAD;
        s_flag[tid] = (wi < W) && (melw[k * W + wi] * mask[k * W + wi] != 0.f);
    }
    __syncthreads();

    const int lane = tid & 63, wave = tid >> 6;
    const int col  = lane & 15, kg  = lane >> 4;
    const bf16x8* bp = (const bf16x8*)(postP + (size_t)k * NKTC * NMT * 512);

    bf16x8 a[NKTC];
    {
        const int jl  = mt * 16 + col;
        const int cc2 = jl >= WPAD, wj = jl - cc2 * WPAD;
        float wt = 0.f;
        if (wj < W) wt = melw[k * W + wj] * mask[k * W + wj];
#pragma unroll
        for (int kt = 0; kt < NKTC; ++kt) {
            bf16x8 av = (bf16x8){0, 0, 0, 0, 0, 0, 0, 0};
            if (wt != 0.f) {
                const float* src = pre_w
                    + ((size_t)k * din + 2 * wj + cc2) * COUT_D + kt * 32 + kg * 8;
                const f4u p0 = *(const f4u*)(src);
                const f4u p1 = *(const f4u*)(src + 4);
#pragma unroll
                for (int e = 0; e < 4; ++e) {
                    av[e]     = (short)f2bf(wt * p0.v[e]);
                    av[e + 4] = (short)f2bf(wt * p1.v[e]);
                }
            }
            a[kt] = av;
        }
    }

    for (int nt = wave; nt < NMT; nt += 4) {
        f32x4 acc = (f32x4){0.f, 0.f, 0.f, 0.f};
#pragma unroll
        for (int kt = 0; kt < NKTC; ++kt)
            acc = __builtin_amdgcn_mfma_f32_16x16x32_bf16(
                a[kt], bp[(kt * NMT + nt) * 64 + lane], acc, 0, 0, 0);
        const int i_loc = nt * 16 + col;
        if (!s_flag[i_loc]) continue;
        const int c  = i_loc >= WPAD, wi = i_loc - c * WPAD;
        const int f  = f0 + wi;
        const int ch = f >> 7, df = f & 127;   // CHUNK = 128
        const int lo = (ch << 7) - WPAD;
        const size_t colIdx = (size_t)(c * CHUNK + df);
#pragma unroll
        for (int reg = 0; reg < 4; ++reg) {
            const int j_loc = mt * 16 + kg * 4 + reg;
            if (!s_flag[j_loc]) continue;
            const int c2 = j_loc >= WPAD, wi2 = j_loc - c2 * WPAD;
            const int jj = f0 + wi2 - lo;      // in [1, 350]
            atomicAdd(Mf + ((size_t)ch * K2 + c2 * WIN + jj) * OC + colIdx,
                      acc[reg]);
        }
    }
}

// ---- convert banded Mf32 -> bf16 B-frags: (chunk, kt, ct, lane, 8)
__global__ __launch_bounds__(256) void bs_mk_bf16(
    const float* __restrict__ Mf, unsigned short* __restrict__ Mb)
{
    const int chunk = blockIdx.x, kt = blockIdx.y;
    for (int q = threadIdx.x; q < NCT * 64; q += 256) {
        const int ct = q >> 6, lane = q & 63;
        const int col = lane & 15, kg = lane >> 4;
        unsigned short v[8];
#pragma unroll
        for (int e = 0; e < 8; ++e) {
            const int jp = kt * 32 + kg * 8 + e;
            v[e] = f2bf(Mf[((size_t)chunk * K2 + jp) * OC + ct * 16 + col]);
        }
        st8(Mb + ((((size_t)chunk * KT2 + kt) * NCT + ct) * 64 + lane) * 8, v);
    }
}

// ---- main: out_row = M . x_window + bias, XCD-swizzled t-tile index.
__global__ __launch_bounds__(1024) void bs_banded(
    const unsigned short* __restrict__ x_bf,
    const unsigned short* __restrict__ Mb,
    const float* __restrict__ bias_g, float* __restrict__ out)
{
    __shared__ unsigned short s_x[M_TILE][SXLD];

    const int chunk = blockIdx.y;                 // t-tile fastest
    // T1 bijective chunked swizzle: 128 t-tiles, 8 XCDs, 16 per XCD
    const int tt     = (blockIdx.x % NXCD) * (NTT / NXCD) + blockIdx.x / NXCD;
    const int m_base = tt * M_TILE;
    const int tid    = threadIdx.x;
    const int lo     = chunk * CHUNK - WPAD;      // f-space window start

    // stage: 32 rows x 2 ch x 44 ushort8 chunks
    for (int p = tid; p < M_TILE * 2 * 44; p += 1024) {
        const int seg = p / 44, q = p - seg * 44;
        const int row = seg >> 1, c = seg & 1;
        const int m = m_base + row, b = m >> 10, t = m & 1023;
        const unsigned short* sr = x_bf + ((size_t)(b * 2 + c) * T_DIM + t) * XP;
        const int fl = lo + 8 * q;
        bf16x8 v;
        if (fl >= 0 && fl + 8 <= XP) {
            v = *(const bf16x8*)(sr + fl);        // 16B-aligned fast path
        } else {                                  // edge chunks: clamp addr
#pragma unroll
            for (int e = 0; e < 8; ++e) {
                const int f = min(max(fl + e, 0), F_DIM - 1);
                v[e] = (short)sr[f];
            }
        }
        *(bf16x8*)&s_x[row][c * WIN + 8 * q] = v;
    }
    __syncthreads();

    const int lane = tid & 63, wave = tid >> 6;   // wave in [0,16) = ct
    const int col  = lane & 15, kg  = lane >> 4;

    f32x4 acc[2];
#pragma unroll
    for (int mf = 0; mf < 2; ++mf) acc[mf] = (f32x4){0.f, 0.f, 0.f, 0.f};

    const bf16x8* bp = (const bf16x8*)(Mb + (size_t)chunk * KT2 * NCT * 512);

    bf16x8 b0, b1, b2, b3;
    b0 = bp[(size_t)(0 * NCT + wave) * 64 + lane];
    b1 = bp[(size_t)(1 * NCT + wave) * 64 + lane];
    b2 = bp[(size_t)(2 * NCT + wave) * 64 + lane];
    b3 = bp[(size_t)(3 * NCT + wave) * 64 + lane];

    bf16x8 aC0 = *(const bf16x8*)&s_x[col][kg * 8];
    bf16x8 aC1 = *(const bf16x8*)&s_x[16 + col][kg * 8];
    bf16x8 aN0, aN1;

#define PH(KT, BUF)                                                            \
    {                                                                          \
        if ((KT) + 1 < KT2) {                                                  \
            aN0 = *(const bf16x8*)&s_x[col][((KT) + 1) * 32 + kg * 8];         \
            aN1 = *(const bf16x8*)&s_x[16 + col][((KT) + 1) * 32 + kg * 8];    \
        }                                                                      \
        acc[0] = __builtin_amdgcn_mfma_f32_16x16x32_bf16(                      \
            aC0, BUF, acc[0], 0, 0, 0);                                        \
        acc[1] = __builtin_amdgcn_mfma_f32_16x16x32_bf16(                      \
            aC1, BUF, acc[1], 0, 0, 0);                                        \
        if ((KT) + 4 < KT2) {                                                  \
            BUF = bp[(size_t)(((KT) + 4) * NCT + wave) * 64 + lane];           \
        }                                                                      \
        aC0 = aN0; aC1 = aN1;                                                  \
    }

    PH(0, b0)  PH(1, b1)  PH(2, b2)  PH(3, b3)
    PH(4, b0)  PH(5, b1)  PH(6, b2)  PH(7, b3)
    PH(8, b0)  PH(9, b1)  PH(10, b2) PH(11, b3)
    PH(12, b0) PH(13, b1) PH(14, b2) PH(15, b3)
    PH(16, b0) PH(17, b1) PH(18, b2) PH(19, b3)
    PH(20, b0) PH(21, b1)
#undef PH

    // epilogue: dense store + bias
    const int b  = m_base >> 10;
    const int t0 = m_base & 1023;
    {
        const int i  = wave * 16 + col;
        const int c  = i >> 7, df = i & 127;
        const int f  = chunk * CHUNK + df;
        if (f < F_DIM) {
            const float bv = bias_g[c * F_DIM + f];
            float* orow = out + ((size_t)(b * 2 + c) * T_DIM + t0) * F_DIM + f;
#pragma unroll
            for (int mf = 0; mf < 2; ++mf)
#pragma unroll
                for (int reg = 0; reg < 4; ++reg) {
                    const int r = mf * 16 + kg * 4 + reg;
                    orow[(size_t)r * F_DIM] = acc[mf][reg] + bv;
                }
        }
    }
}

extern "C" void kernel_launch(void* const* d_in, const int* in_sizes, int n_in,
                              void* d_out, int out_size, void* d_ws, size_t ws_size,
                              hipStream_t stream) {
    const float* x      = (const float*)d_in[0];
    const float* pre_w  = (const float*)d_in[1];
    const float* pre_b  = (const float*)d_in[2];
    const float* post_w = (const float*)d_in[3];
    const float* post_b = (const float*)d_in[4];
    const int*   idx    = (const int*)d_in[5];
    const float* melw   = (const float*)d_in[6];
    const float* mask   = (const float*)d_in[7];
    const float* ola    = (const float*)d_in[8];
    float* out = (float*)d_out;

    const int W   = in_sizes[5] / K_BANDS;   // <= 112
    const int din = 2 * W;

    // workspace: Mf | bias | postP | Mb | x_bf   (~30.3 MB)
    const size_t mf_bytes   = (size_t)NCHUNK * K2 * OC * 4;          // 6,488,064
    const size_t bias_bytes = 8448;
    float*          Mf     = (float*)d_ws;
    float*          bias_g = (float*)((char*)d_ws + mf_bytes);
    unsigned short* postP  = (unsigned short*)((char*)d_ws + mf_bytes + bias_bytes);
    const size_t frag_bytes = (size_t)K_BANDS * NKTC * NMT * 64 * 8 * 2; // 3,670,016
    unsigned short* Mb     = (unsigned short*)((char*)postP + frag_bytes);
    const size_t mb_bytes   = (size_t)NCHUNK * KT2 * NCT * 64 * 8 * 2;   // 3,244,032
    unsigned short* x_bf   = (unsigned short*)((char*)Mb + mb_bytes);

    const int zcount = (int)((mf_bytes + bias_bytes) / 4);

    bs_front<<<K_BANDS * NKTC, 256, 0, stream>>>(
        post_w, idx, melw, mask, ola, postP, (float*)d_ws, zcount, W, din);
    bs_mid<<<NCOMP + NCVT, 256, 0, stream>>>(
        postP, pre_w, pre_b, post_w, post_b, idx, melw, mask, ola,
        Mf, bias_g, x, x_bf, W, din);
    bs_mk_bf16<<<dim3(NCHUNK, KT2), 256, 0, stream>>>(Mf, Mb);

    bs_banded<<<dim3(NTT, NCHUNK), 1024, 0, stream>>>(
        x_bf, Mb, bias_g, out);
}